// Round 1
// 1366.668 us; speedup vs baseline: 1.4305x; 1.4305x over previous
//
#include <hip/hip_runtime.h>
#include <cstdint>
#include <cstddef>

// Sinkhorn: B=64, P=1024, T=1024, 50 iterations.
// R3: ONE fused kernel per iteration. It reads fp8 K once, computes
// v = tgt/Ktu from the incoming accumulator, updates u rows (wave-reduce),
// and accumulates K^T u_new into the NEXT iteration's accumulator via
// per-wave LDS partials + f32 global atomics. 3-buffer acc rotation
// (read i%3, accumulate (i+1)%3, zero (i+2)%3) needs no memset launches.
// bf16 K16 removed: final P recomputed from C in f32 (better precision).
// Iteration HBM traffic: 2x64MB -> 1x64MB per iter; launches 103 -> 54.

#define DEVI static __device__ __forceinline__

// fp8 e4m3 encode (sign=0). Input pre-scaled by 256: f in (0, 256].
DEVI unsigned char f2fp8(float f) {
    if (f >= 0.015625f) {                      // normal fp8
        unsigned u = __float_as_uint(f);
        u += 0x7FFFFu + ((u >> 20) & 1u);      // RNE into 3-bit mantissa
        int e = (int)(u >> 23) - 127;
        return (unsigned char)(((e + 7) << 3) | ((u >> 20) & 7u));
    } else {                                   // subnormal: round(f*512)
        int n = (int)(f * 512.0f + 0.5f);      // n==8 aliases to e=1,m=0: correct
        return (unsigned char)n;
    }
}
// raw decode: returns K * 2^-112 (sums multiplied by 2^112 once)
DEVI float fp8raw(unsigned b) { return __uint_as_float((b & 0x7Fu) << 20); }
#define FP8_SCALE 0x1.0p112f

// native global_atomic_add_f32 (avoids CAS-loop lowering; denorm-flush on
// raw-scale terms loses only K < 6.1e-5 contributions: ~1e-5 relative).
DEVI void atomicAddF(float* p, float v) {
#ifdef __HIP_PLATFORM_AMD__
    unsafeAtomicAdd(p, v);
#else
    atomicAdd(p, v);
#endif
}

__global__ __launch_bounds__(256) void k_zero(float* __restrict__ p, int n) {
    int i = blockIdx.x * 256 + threadIdx.x;
    if (i < n) p[i] = 0.0f;
}
__global__ __launch_bounds__(256) void k_ones(float* __restrict__ p, int n) {
    int i = blockIdx.x * 256 + threadIdx.x;
    if (i < n) p[i] = 1.0f;
}

// exp + fp8 encode + fold in acc0 = K^T 1 (u0 = ones) via atomics.
// grid 1024: block x -> batch x>>4, rows (x&15)+16k, k=0..63.
// thread tid covers t = 4*tid..4*tid+3 for every row it visits, so the
// 4 column partial sums live in registers across all 64 rows.
__global__ __launch_bounds__(256) void k_exp8c(const float4* __restrict__ C4,
        const float* __restrict__ regp, unsigned* __restrict__ K8,
        float* __restrict__ acc0) {
    const float negi = -1.0f / regp[0];
    const int tid = threadIdx.x;
    const int b = blockIdx.x >> 4;
    const int r0 = blockIdx.x & 15;
    float a0 = 0.f, a1 = 0.f, a2 = 0.f, a3 = 0.f;
    const size_t bbase = (((size_t)b) << 18) + tid;   // float4 units
    #pragma unroll 4
    for (int k = 0; k < 64; ++k) {
        const size_t idx = bbase + ((size_t)((k << 4) + r0) << 8);
        float4 c = C4[idx];
        unsigned p = (unsigned)f2fp8(__expf(c.x * negi) * 256.f)
                   | ((unsigned)f2fp8(__expf(c.y * negi) * 256.f) << 8)
                   | ((unsigned)f2fp8(__expf(c.z * negi) * 256.f) << 16)
                   | ((unsigned)f2fp8(__expf(c.w * negi) * 256.f) << 24);
        K8[idx] = p;
        a0 += fp8raw(p);       a1 += fp8raw(p >> 8);
        a2 += fp8raw(p >> 16); a3 += fp8raw(p >> 24);
    }
    float* a = acc0 + (b << 10) + (tid << 2);
    atomicAddF(a + 0, a0); atomicAddF(a + 1, a1);
    atomicAddF(a + 2, a2); atomicAddF(a + 3, a3);
}

// Fused Sinkhorn step. grid 1024 x 256 (16 blocks/batch, 64 rows/block,
// 4 waves x 16 rows). Reads acc_in (raw Ktu for current u), writes u_new,
// atomically accumulates raw K^T u_new into acc_out, zeros acc_z slice.
__global__ __launch_bounds__(256) void k_fused(const unsigned char* __restrict__ K8,
        const float* __restrict__ acc_in, float* __restrict__ acc_out,
        float* __restrict__ acc_z,
        const float* __restrict__ tgt, const float* __restrict__ pred,
        float* __restrict__ u) {
    __shared__ float sv[1024];
    __shared__ float red[4 * 1088];   // per-wave partials, stride 17/lane: 2-way banks only
    const int tid = threadIdx.x;
    const int b = blockIdx.x >> 4;
    const int rb = blockIdx.x & 15;
    {   // v[t] = tgt/(acc_in*SCALE); acc_in row is 4KB, L2-hot (16 readers)
        const float* ai = acc_in + (b << 10);
        const float* tg = tgt + (b << 10);
        #pragma unroll
        for (int q = 0; q < 4; ++q) {
            const int t = tid + (q << 8);
            sv[t] = tg[t] / (ai[t] * FP8_SCALE);
        }
        // zero the iteration-(i+1) accumulate target (stream-ordered: safe)
        if (tid < 64) acc_z[(blockIdx.x << 6) + tid] = 0.f;
    }
    __syncthreads();
    const int w = tid >> 6, l = tid & 63;
    const int row0 = (b << 10) + (rb << 6) + (w << 4);
    const float4 v0 = *(const float4*)(sv + (l << 4));
    const float4 v1 = *(const float4*)(sv + (l << 4) + 4);
    const float4 v2 = *(const float4*)(sv + (l << 4) + 8);
    const float4 v3 = *(const float4*)(sv + (l << 4) + 12);
    float r00=0,r01=0,r02=0,r03=0,r04=0,r05=0,r06=0,r07=0;
    float r08=0,r09=0,r10=0,r11=0,r12=0,r13=0,r14=0,r15=0;
    #pragma unroll 2
    for (int r = 0; r < 16; ++r) {
        const size_t row = (size_t)row0 + r;
        const uint4 k = ((const uint4*)(K8 + (row << 10)))[l];
        const float f0 = fp8raw(k.x),       f1 = fp8raw(k.x >> 8);
        const float f2 = fp8raw(k.x >> 16), f3 = fp8raw(k.x >> 24);
        const float f4 = fp8raw(k.y),       f5 = fp8raw(k.y >> 8);
        const float f6 = fp8raw(k.y >> 16), f7 = fp8raw(k.y >> 24);
        const float f8 = fp8raw(k.z),       f9 = fp8raw(k.z >> 8);
        const float fa = fp8raw(k.z >> 16), fb = fp8raw(k.z >> 24);
        const float fc = fp8raw(k.w),       fd = fp8raw(k.w >> 8);
        const float fe = fp8raw(k.w >> 16), ff = fp8raw(k.w >> 24);
        float s = f0*v0.x + f1*v0.y + f2*v0.z + f3*v0.w
                + f4*v1.x + f5*v1.y + f6*v1.z + f7*v1.w
                + f8*v2.x + f9*v2.y + fa*v2.z + fb*v2.w
                + fc*v3.x + fd*v3.y + fe*v3.z + ff*v3.w;
        #pragma unroll
        for (int m = 32; m >= 1; m >>= 1) s += __shfl_xor(s, m, 64);
        const float un = pred[row] / (s * FP8_SCALE);
        if (l == 0) u[row] = un;
        r00 += f0*un; r01 += f1*un; r02 += f2*un; r03 += f3*un;
        r04 += f4*un; r05 += f5*un; r06 += f6*un; r07 += f7*un;
        r08 += f8*un; r09 += f9*un; r10 += fa*un; r11 += fb*un;
        r12 += fc*un; r13 += fd*un; r14 += fe*un; r15 += ff*un;
    }
    {   // lane l owns t = 16l+j; stride-17 layout: bank = (17l+j)%32, 2-way only
        const int base = w * 1088 + l * 17;
        red[base + 0] = r00;  red[base + 1] = r01;  red[base + 2] = r02;  red[base + 3] = r03;
        red[base + 4] = r04;  red[base + 5] = r05;  red[base + 6] = r06;  red[base + 7] = r07;
        red[base + 8] = r08;  red[base + 9] = r09;  red[base + 10] = r10; red[base + 11] = r11;
        red[base + 12] = r12; red[base + 13] = r13; red[base + 14] = r14; red[base + 15] = r15;
    }
    __syncthreads();
    float* ao = acc_out + (b << 10);
    #pragma unroll
    for (int q = 0; q < 4; ++q) {
        const int t = tid + (q << 8);
        const int idx = (t >> 4) * 17 + (t & 15);
        float s2 = red[idx] + red[idx + 1088] + red[idx + 2176] + red[idx + 3264];
        atomicAddF(ao + t, s2);   // 1024/block, 16 adds per address total
    }
}

__global__ __launch_bounds__(256) void k_vfin(const float* __restrict__ acc,
        const float* __restrict__ tgt, float* __restrict__ v, int n) {
    int i = blockIdx.x * 256 + threadIdx.x;
    if (i < n) v[i] = tgt[i] / (acc[i] * FP8_SCALE);
}

// P = u * exp(-C/reg) * v  (f32 K: better than the old bf16-K path)
__global__ __launch_bounds__(256) void k_poutC(const float* __restrict__ C,
        const float* __restrict__ regp, const float* __restrict__ u,
        const float* __restrict__ v, float* __restrict__ out) {
    const size_t row = blockIdx.x;
    const int b = (int)(row >> 10);
    const int t = threadIdx.x << 2;
    const float up = u[row];
    const float negi = -1.0f / regp[0];
    const float4 vv = *(const float4*)(v + (b << 10) + t);
    const float4 c4 = *(const float4*)(C + (row << 10) + t);
    float4 o = make_float4(up * __expf(c4.x * negi) * vv.x,
                           up * __expf(c4.y * negi) * vv.y,
                           up * __expf(c4.z * negi) * vv.z,
                           up * __expf(c4.w * negi) * vv.w);
    *(float4*)(out + (row << 10) + t) = o;
}

// ---- fallback path (tiny workspace): recompute exp from C each pass ----
__global__ __launch_bounds__(256) void k_ktuC(const float* __restrict__ C,
        const float* __restrict__ regp, const float* __restrict__ u,
        const float* __restrict__ tgt, float* __restrict__ v) {
    __shared__ float su[1024];
    __shared__ float4 red[256];
    const int b = blockIdx.y;
    const int t0 = blockIdx.x * 128;
    const int tid = threadIdx.x;
    ((float4*)su)[tid] = ((const float4*)(u + (b << 10)))[tid];
    __syncthreads();
    const int tt = tid & 31;
    const int pg = tid >> 5;
    const int t = t0 + tt * 4;
    float4 acc = make_float4(0.f, 0.f, 0.f, 0.f);
    const float negi = -1.0f / regp[0];
    const float* Cp = C + (((size_t)b) << 20) + ((size_t)pg << 10) + t;
    #pragma unroll 4
    for (int p = pg; p < 1024; p += 8) {
        float4 c4 = *(const float4*)Cp;
        float up = su[p];
        acc.x += __expf(c4.x * negi) * up;
        acc.y += __expf(c4.y * negi) * up;
        acc.z += __expf(c4.z * negi) * up;
        acc.w += __expf(c4.w * negi) * up;
        Cp += (size_t)8 << 10;
    }
    red[tid] = acc;
    __syncthreads();
    if (tid < 32) {
        float4 s = red[tid];
        #pragma unroll
        for (int g = 1; g < 8; ++g) {
            float4 r = red[tid + (g << 5)];
            s.x += r.x; s.y += r.y; s.z += r.z; s.w += r.w;
        }
        const int tw = t0 + tid * 4;
        const float4 tg = *(const float4*)(tgt + (b << 10) + tw);
        *(float4*)(v + (b << 10) + tw) =
            make_float4(tg.x / s.x, tg.y / s.y, tg.z / s.z, tg.w / s.w);
    }
}

__global__ __launch_bounds__(256) void k_kvC(const float* __restrict__ C,
        const float* __restrict__ regp, const float* __restrict__ v,
        const float* __restrict__ pred, float* __restrict__ u) {
    __shared__ float sv[1024];
    const int tid = threadIdx.x;
    const int row0 = blockIdx.x << 2;
    const int b = row0 >> 10;
    ((float4*)sv)[tid] = ((const float4*)(v + (b << 10)))[tid];
    __syncthreads();
    const int w = tid >> 6, l = tid & 63;
    const size_t row = (size_t)row0 + w;
    float s = 0.f;
    const float negi = -1.0f / regp[0];
    const float* Cr = C + (row << 10);
    #pragma unroll
    for (int i = 0; i < 4; ++i) {
        const int t = (i << 8) + (l << 2);
        float4 c4 = *(const float4*)(Cr + t);
        float4 vv = *(const float4*)(sv + t);
        s += __expf(c4.x * negi) * vv.x + __expf(c4.y * negi) * vv.y
           + __expf(c4.z * negi) * vv.z + __expf(c4.w * negi) * vv.w;
    }
    #pragma unroll
    for (int m = 32; m >= 1; m >>= 1) s += __shfl_xor(s, m, 64);
    if (l == 0) u[row] = pred[row] / s;
}

extern "C" void kernel_launch(void* const* d_in, const int* in_sizes, int n_in,
                              void* d_out, int out_size, void* d_ws, size_t ws_size,
                              hipStream_t stream) {
    const float* pred = (const float*)d_in[0];
    const float* tgt  = (const float*)d_in[1];
    const float* C    = (const float*)d_in[2];
    const float* regp = (const float*)d_in[3];
    float* out = (float*)d_out;

    const size_t k8b = (size_t)64 * 1024 * 1024;          // 64 MB fp8 K
    const size_t needed = k8b + (size_t)(3 * 65536 + 2 * 65536) * 4;
    char* ws = (char*)d_ws;
    const dim3 blk(256);

    if (ws_size >= needed) {
        unsigned char* K8 = (unsigned char*)ws;
        float* accs = (float*)(ws + k8b);                 // acc[3][65536]
        float* u = accs + 3 * 65536;
        float* v = u + 65536;

        k_zero<<<dim3(768), blk, 0, stream>>>(accs, 3 * 65536);
        k_exp8c<<<dim3(1024), blk, 0, stream>>>((const float4*)C, regp,
                (unsigned*)K8, accs);                     // acc0 = K^T 1
        for (int it = 0; it < 50; ++it) {
            float* ain = accs + (size_t)(it % 3) * 65536;
            float* aout = accs + (size_t)((it + 1) % 3) * 65536;
            float* az = accs + (size_t)((it + 2) % 3) * 65536;
            k_fused<<<dim3(1024), blk, 0, stream>>>(K8, ain, aout, az,
                    tgt, pred, u);
        }
        // after it=49: acc[(49+1)%3] = acc[2] holds K^T u_50
        k_vfin<<<dim3(256), blk, 0, stream>>>(accs + 2 * 65536, tgt, v, 65536);
        k_poutC<<<dim3(65536), blk, 0, stream>>>(C, regp, u, v, out);
    } else {
        float* u = (float*)ws;
        float* v = u + 65536;
        k_ones<<<dim3(256), blk, 0, stream>>>(u, 65536);
        for (int it = 0; it < 50; ++it) {
            k_ktuC<<<dim3(8, 64), blk, 0, stream>>>(C, regp, u, tgt, v);
            k_kvC<<<dim3(16384), blk, 0, stream>>>(C, regp, v, pred, u);
        }
        k_ktuC<<<dim3(8, 64), blk, 0, stream>>>(C, regp, u, tgt, v);
        k_poutC<<<dim3(65536), blk, 0, stream>>>(C, regp, u, v, out);
    }
}